// Round 1
// 185.996 us; speedup vs baseline: 1.0592x; 1.0592x over previous
//
#include <hip/hip_runtime.h>

// Problem constants
#define NB 2        // batch
#define NPTS 1024   // points per cloud
#define NGEN 65536  // G * D_IN generated points per batch

// ws layout (float offsets), all 16B-aligned where accessed as float4.
#define OFF_GW    0        // 8192
#define OFF_H1P   8192     // 24576 (24 k-chunks x 2 b x 512 j)
#define OFF_D2H   32768    // 65536
#define OFF_S4    98304    // 8192
#define OFF_Y4    106496   // 524288
#define OFF_WT4   630784   // 1572864 (3*128*1024 float4)
#define OFF_MPART 2203648  // 131072
// total 2334720 floats = 9.34 MB

// ---------------- KA: init + S4 pack + gw + Wd3 transpose + enc1 ----------------
// blocks 0..63: gw + S4 pack; 64..1599: transpose Wd3 -> Wt4[c][k4][p];
// 1600..1695: encoder L1 k-split partials (non-atomic).
__global__ __launch_bounds__(256) void kA_init(
    const float* __restrict__ x, const float* __restrict__ grid,
    const float* __restrict__ Wd1, const float* __restrict__ Wd3,
    const float* __restrict__ We1,
    float* __restrict__ gw, float* __restrict__ S4,
    float4* __restrict__ Wt4, float* __restrict__ h1part) {
  if (blockIdx.x < 64) {
    int t = blockIdx.x * 256 + threadIdx.x;
    if (t < 8192) {
      int g = t >> 7, j = t & 127;
      float a = grid[g * 3 + 0] * Wd1[64 * 128 + j]
              + grid[g * 3 + 1] * Wd1[65 * 128 + j]
              + grid[g * 3 + 2] * Wd1[66 * 128 + j];
      gw[t] = a;
    } else if (t < 10240) {
      int p = t - 8192;
      const float* xp = x + p * 3;
      float s0 = xp[0], s1 = xp[1], s2 = xp[2];
      ((float4*)S4)[p] = make_float4(s0, s1, s2, s0 * s0 + s1 * s1 + s2 * s2);
    }
  } else if (blockIdx.x < 1600) {
    int tid = (blockIdx.x - 64) * 256 + threadIdx.x;  // 0..393215
    int p  = tid & 1023;
    int k4 = (tid >> 10) & 127;
    int c  = tid >> 17;                               // 0..2
    const float* W = Wd3 + (k4 * 4) * 3072 + p * 3 + c;
    float w0 = W[0], w1 = W[3072], w2 = W[2 * 3072], w3 = W[3 * 3072];
    Wt4[(c * 128 + k4) * 1024 + p] = make_float4(w0, w1, w2, w3);
  } else {
    // enc1: 96 blocks = 24 kc x 2 jh x 2 b; 256 threads each.
    int idx = blockIdx.x - 1600;                      // 0..95
    int kc = idx % 24;
    int rest = idx / 24;                              // 0..3
    int jh = rest & 1;
    int b  = rest >> 1;
    int j = jh * 256 + threadIdx.x;
    const float* xb = x + b * 3072 + kc * 128;        // uniform -> s_load
    const float* W  = We1 + (kc * 128) * 512 + j;
    float acc = 0.f;
#pragma unroll 8
    for (int k = 0; k < 128; ++k) acc += xb[k] * W[k * 512];
    h1part[kc * 1024 + b * 512 + j] = acc;            // non-atomic partial
  }
}

// ---------------- KB: enc2 + enc3 + zw + dec2 fused ----------------
// 128 blocks = (b,g); each block redundantly computes the tiny encoder tail
// for its b (~0.3us of parallel work), then dec2 for its g.
__global__ __launch_bounds__(256) void kB_enc_dec2(
    const float* __restrict__ h1part, const float* __restrict__ be1,
    const float* __restrict__ We2, const float* __restrict__ be2,
    const float* __restrict__ We3, const float* __restrict__ be3,
    const float* __restrict__ Wd1, const float* __restrict__ bd1,
    const float* __restrict__ gw,
    const float* __restrict__ Wd2, const float* __restrict__ bd2,
    float* __restrict__ d2h) {
  __shared__ float h1l[512];
  __shared__ float h2p[2][128];
  __shared__ float h2l[128];
  __shared__ float zl[64];
  __shared__ float d1[128];
  int bg = blockIdx.x;
  int b = bg >> 6, g = bg & 63;
  int t = threadIdx.x;
  // h1 = relu(sum of 24 k-chunk partials + be1)
#pragma unroll
  for (int i = 0; i < 2; ++i) {
    int k = i * 256 + t;
    float a = be1[k];
#pragma unroll
    for (int kc = 0; kc < 24; ++kc) a += h1part[kc * 1024 + b * 512 + k];
    h1l[k] = fmaxf(a, 0.f);
  }
  __syncthreads();
  // h2 partial: thread (half, j) does 256-length half-dot
  {
    int j = t & 127, half = t >> 7;
    const float* W = We2 + (half * 256) * 128 + j;
    const float* h = h1l + half * 256;
    float a = 0.f;
#pragma unroll 8
    for (int k = 0; k < 256; ++k) a += h[k] * W[k * 128];
    h2p[half][j] = a;
  }
  __syncthreads();
  if (t < 128) h2l[t] = fmaxf(h2p[0][t] + h2p[1][t] + be2[t], 0.f);
  __syncthreads();
  // z = relu(h2 @ We3 + be3)
  if (t < 64) {
    float a = be3[t];
#pragma unroll 4
    for (int k = 0; k < 128; ++k) a += h2l[k] * We3[k * 64 + t];
    zl[t] = fmaxf(a, 0.f);
  }
  __syncthreads();
  // d1 = relu(z @ Wd1[0:64] + bd1 + gw[g])
  if (t < 128) {
    float a = bd1[t];
#pragma unroll 4
    for (int k = 0; k < 64; ++k) a += zl[k] * Wd1[k * 128 + t];
    d1[t] = fmaxf(a + gw[g * 128 + t], 0.f);
  }
  __syncthreads();
  // dec2
  float a0 = bd2[t], a1 = bd2[t + 256];
#pragma unroll 4
  for (int k = 0; k < 128; ++k) {
    float dv = d1[k];
    a0 += dv * Wd2[k * 512 + t];
    a1 += dv * Wd2[k * 512 + t + 256];
  }
  float* o = d2h + bg * 512;
  o[t] = fmaxf(a0, 0.f);
  o[t + 256] = fmaxf(a1, 0.f);
}

// ---------------- KC: decoder L3 + tanh + (-2y, |y|^2) pack (k-split) ----------------
// 256 blocks = rt(16) x pg(16); 512 threads = 8 waves. Wave w owns k4 range
// [16w,16w+16) for ALL 8 rows -> each Wt4 word is loaded exactly once per
// block (was 4x redundant). LDS partial-combine at the end.
// Also zeroes out[0] (runs strictly before KD on the stream).
__global__ __launch_bounds__(512) void kC_dec3_y4(
    const float* __restrict__ d2h, const float4* __restrict__ Wt4,
    const float* __restrict__ bd3, float4* __restrict__ Y4,
    float* __restrict__ out) {
  __shared__ float4 a_lds[8 * 128];        // 8 rows x 512 k = 16 KB
  __shared__ float part[8 * 3 * 8 * 64];   // [r][c][w][lane] = 48 KB
  int rt = blockIdx.x >> 4;
  int pg = blockIdx.x & 15;
  int t = threadIdx.x;
  if (blockIdx.x == 0 && t == 0) out[0] = 0.f;
  {
    const float4* src = (const float4*)d2h + rt * 1024;
#pragma unroll
    for (int i = 0; i < 2; ++i) a_lds[i * 512 + t] = src[i * 512 + t];
  }
  __syncthreads();
  int lane = t & 63, w = t >> 6;           // w = 0..7
  int p = pg * 64 + lane;
  const float4* wp0 = Wt4 + p;             // c=0
  const float4* wp1 = Wt4 + 131072 + p;    // c=1
  const float4* wp2 = Wt4 + 262144 + p;    // c=2
  float acc[8][3];
#pragma unroll
  for (int r = 0; r < 8; ++r)
#pragma unroll
    for (int c = 0; c < 3; ++c) acc[r][c] = 0.f;
  int kbase = w * 16;
#pragma unroll 4
  for (int i = 0; i < 16; ++i) {
    int k4 = kbase + i;
    float4 w0 = wp0[k4 * 1024];
    float4 w1 = wp1[k4 * 1024];
    float4 w2 = wp2[k4 * 1024];
#pragma unroll
    for (int r = 0; r < 8; ++r) {
      float4 A = a_lds[r * 128 + k4];      // wave-uniform broadcast
      acc[r][0] += A.x * w0.x + A.y * w0.y + A.z * w0.z + A.w * w0.w;
      acc[r][1] += A.x * w1.x + A.y * w1.y + A.z * w1.z + A.w * w1.w;
      acc[r][2] += A.x * w2.x + A.y * w2.y + A.z * w2.z + A.w * w2.w;
    }
  }
#pragma unroll
  for (int r = 0; r < 8; ++r)
#pragma unroll
    for (int c = 0; c < 3; ++c)
      part[((r * 3 + c) * 8 + w) * 64 + lane] = acc[r][c];
  __syncthreads();
  // combine: thread (w,lane) -> output row w, col p
  {
    int r = w;
    float s0 = 0.f, s1 = 0.f, s2 = 0.f;
#pragma unroll
    for (int ww = 0; ww < 8; ++ww) {
      s0 += part[((r * 3 + 0) * 8 + ww) * 64 + lane];
      s1 += part[((r * 3 + 1) * 8 + ww) * 64 + lane];
      s2 += part[((r * 3 + 2) * 8 + ww) * 64 + lane];
    }
    float b0 = bd3[p * 3], b1 = bd3[p * 3 + 1], b2 = bd3[p * 3 + 2];
    float y0 = tanhf(s0 + b0), y1 = tanhf(s1 + b1), y2 = tanhf(s2 + b2);
    int row = rt * 8 + r;
    Y4[row * 1024 + p] = make_float4(-2.f * y0, -2.f * y1, -2.f * y2,
                                     y0 * y0 + y1 * y1 + y2 * y2);
  }
}

// ---------------- KD: merged chamfer, 4 insts/pair (unchanged hot loop) ----------------
// blocks 0..255: dir1 (sum_n min_m), blocks 256..511: dir2 partial mins.
// Exactly 2048 waves = 2 waves/SIMD.
__global__ __launch_bounds__(256) void kD_chamfer(
    const float4* __restrict__ Y4, const float4* __restrict__ S4,
    float* __restrict__ mpart, float* __restrict__ out) {
  __shared__ float4 c_lds[1024];           // 16 KB inner cloud
  int t = threadIdx.x;
  if (blockIdx.x < 256) {
    // ---- dir1: resident my = (-2y, |y|^2); LDS = S (plain, |s|^2) ----
    int b = blockIdx.x >> 7, nt = blockIdx.x & 127;
    {
      const float4* src = S4 + b * 1024;
#pragma unroll
      for (int i = 0; i < 4; ++i) c_lds[i * 256 + t] = src[i * 256 + t];
    }
    float4 my0 = Y4[b * 65536 + nt * 512 + t];
    float4 my1 = Y4[b * 65536 + nt * 512 + 256 + t];
    __syncthreads();
    float mn0 = __builtin_inff(), mn1 = mn0;
#pragma unroll 8
    for (int m = 0; m < 1024; ++m) {
      float4 s = c_lds[m];                 // block-uniform broadcast
      float d0 = __builtin_fmaf(s.x, my0.x,
                 __builtin_fmaf(s.y, my0.y,
                 __builtin_fmaf(s.z, my0.z, s.w)));
      float d1 = __builtin_fmaf(s.x, my1.x,
                 __builtin_fmaf(s.y, my1.y,
                 __builtin_fmaf(s.z, my1.z, s.w)));
      mn0 = fminf(mn0, d0);
      mn1 = fminf(mn1, d1);
    }
    float v = (mn0 + my0.w) + (mn1 + my1.w);
#pragma unroll
    for (int off = 32; off > 0; off >>= 1) v += __shfl_down(v, off);
    __shared__ float bsum[4];
    int lane = t & 63, w = t >> 6;
    if (lane == 0) bsum[w] = v;
    __syncthreads();
    if (t == 0) atomicAdd(out, bsum[0] + bsum[1] + bsum[2] + bsum[3]);
  } else {
    // ---- dir2: resident s (plain); LDS = Y' = (-2y, |y|^2) ----
    int blk = blockIdx.x - 256;            // 0..255
    int b   = blk >> 7;
    int mg  = (blk >> 6) & 1;
    int nch = blk & 63;
    {
      const float4* src = Y4 + b * 65536 + nch * 1024;
#pragma unroll
      for (int i = 0; i < 4; ++i) c_lds[i * 256 + t] = src[i * 256 + t];
    }
    float4 s0 = S4[b * 1024 + mg * 512 + t];
    float4 s1 = S4[b * 1024 + mg * 512 + 256 + t];
    __syncthreads();
    float mn0 = __builtin_inff(), mn1 = mn0;
#pragma unroll 8
    for (int n = 0; n < 1024; ++n) {
      float4 y = c_lds[n];
      float d0 = __builtin_fmaf(y.x, s0.x,
                 __builtin_fmaf(y.y, s0.y,
                 __builtin_fmaf(y.z, s0.z, y.w)));
      float d1 = __builtin_fmaf(y.x, s1.x,
                 __builtin_fmaf(y.y, s1.y,
                 __builtin_fmaf(y.z, s1.z, y.w)));
      mn0 = fminf(mn0, d0);
      mn1 = fminf(mn1, d1);
    }
    int base = (nch * 2 + b) * 1024 + mg * 512;
    mpart[base + t]       = mn0 + s0.w;
    mpart[base + 256 + t] = mn1 + s1.w;
  }
}

// ---------------- KE: dir2 final reduce ----------------
// 8 blocks x 256; thread = one (b,m); min over 64 chunks then sum.
__global__ __launch_bounds__(256) void kE_dir2_reduce(
    const float* __restrict__ mpart, float* __restrict__ out) {
  int gid = blockIdx.x * 256 + threadIdx.x;   // 0..2047
  int b = gid >> 10, m = gid & 1023;
  float v = __builtin_inff();
#pragma unroll 8
  for (int ch = 0; ch < 64; ++ch)
    v = fminf(v, mpart[(ch * 2 + b) * 1024 + m]);  // coalesced over m
#pragma unroll
  for (int off = 32; off > 0; off >>= 1) v += __shfl_down(v, off);
  __shared__ float bsum[4];
  int lane = threadIdx.x & 63, w = threadIdx.x >> 6;
  if (lane == 0) bsum[w] = v;
  __syncthreads();
  if (threadIdx.x == 0) atomicAdd(out, bsum[0] + bsum[1] + bsum[2] + bsum[3]);
}

extern "C" void kernel_launch(void* const* d_in, const int* in_sizes, int n_in,
                              void* d_out, int out_size, void* d_ws, size_t ws_size,
                              hipStream_t stream) {
  const float* x   = (const float*)d_in[0];
  const float* grd = (const float*)d_in[1];
  const float* We1 = (const float*)d_in[2];
  const float* be1 = (const float*)d_in[3];
  const float* We2 = (const float*)d_in[4];
  const float* be2 = (const float*)d_in[5];
  const float* We3 = (const float*)d_in[6];
  const float* be3 = (const float*)d_in[7];
  const float* Wd1 = (const float*)d_in[8];
  const float* bd1 = (const float*)d_in[9];
  const float* Wd2 = (const float*)d_in[10];
  const float* bd2 = (const float*)d_in[11];
  const float* Wd3 = (const float*)d_in[12];
  const float* bd3 = (const float*)d_in[13];
  float* ws = (float*)d_ws;
  float* out = (float*)d_out;

  float* gw     = ws + OFF_GW;
  float* h1part = ws + OFF_H1P;
  float* d2h    = ws + OFF_D2H;
  float* S4     = ws + OFF_S4;
  float* Y4     = ws + OFF_Y4;
  float4* Wt4   = (float4*)(ws + OFF_WT4);
  float* mpart  = ws + OFF_MPART;

  hipLaunchKernelGGL(kA_init, dim3(1696), dim3(256), 0, stream,
                     x, grd, Wd1, Wd3, We1, gw, S4, Wt4, h1part);
  hipLaunchKernelGGL(kB_enc_dec2, dim3(128), dim3(256), 0, stream,
                     h1part, be1, We2, be2, We3, be3, Wd1, bd1, gw, Wd2, bd2,
                     d2h);
  hipLaunchKernelGGL(kC_dec3_y4, dim3(256), dim3(512), 0, stream,
                     d2h, Wt4, bd3, (float4*)Y4, out);
  hipLaunchKernelGGL(kD_chamfer, dim3(512), dim3(256), 0, stream,
                     (const float4*)Y4, (const float4*)S4, mpart, out);
  hipLaunchKernelGGL(kE_dir2_reduce, dim3(8), dim3(256), 0, stream,
                     mpart, out);
}

// Round 2
// 165.807 us; speedup vs baseline: 1.1882x; 1.1218x over previous
//
#include <hip/hip_runtime.h>

// Problem constants
#define NB 2        // batch
#define NPTS 1024   // points per cloud
#define NGEN 65536  // G * D_IN generated points per batch

// ws layout (float offsets), all 16B-aligned where accessed as float4.
#define OFF_GW    0        // 8192
#define OFF_H1P   8192     // 24576 (24 k-chunks x 2 b x 512 j)
#define OFF_ZW    32768    // 256 (pad to 512)
#define OFF_S4    33280    // 8192
#define OFF_Y4    41472    // 524288
#define OFF_WT4   565760   // 1572864 (3*128*1024 float4)
#define OFF_MPART 2138624  // 131072
// total 2269696 floats = 9.08 MB

// ---------------- KA: init + S4 pack + gw + Wd3 transpose + enc1 ----------------
// blocks 0..63: gw + S4 pack; 64..1599: transpose Wd3 -> Wt4[c][k4][p];
// 1600..1695: encoder L1 k-split partials (non-atomic).
__global__ __launch_bounds__(256) void kA_init(
    const float* __restrict__ x, const float* __restrict__ grid,
    const float* __restrict__ Wd1, const float* __restrict__ Wd3,
    const float* __restrict__ We1,
    float* __restrict__ gw, float* __restrict__ S4,
    float4* __restrict__ Wt4, float* __restrict__ h1part) {
  if (blockIdx.x < 64) {
    int t = blockIdx.x * 256 + threadIdx.x;
    if (t < 8192) {
      int g = t >> 7, j = t & 127;
      float a = grid[g * 3 + 0] * Wd1[64 * 128 + j]
              + grid[g * 3 + 1] * Wd1[65 * 128 + j]
              + grid[g * 3 + 2] * Wd1[66 * 128 + j];
      gw[t] = a;
    } else if (t < 10240) {
      int p = t - 8192;
      const float* xp = x + p * 3;
      float s0 = xp[0], s1 = xp[1], s2 = xp[2];
      ((float4*)S4)[p] = make_float4(s0, s1, s2, s0 * s0 + s1 * s1 + s2 * s2);
    }
  } else if (blockIdx.x < 1600) {
    int tid = (blockIdx.x - 64) * 256 + threadIdx.x;  // 0..393215
    int p  = tid & 1023;
    int k4 = (tid >> 10) & 127;
    int c  = tid >> 17;                               // 0..2
    const float* W = Wd3 + (k4 * 4) * 3072 + p * 3 + c;
    float w0 = W[0], w1 = W[3072], w2 = W[2 * 3072], w3 = W[3 * 3072];
    Wt4[(c * 128 + k4) * 1024 + p] = make_float4(w0, w1, w2, w3);
  } else {
    // enc1: 96 blocks = 24 kc x 2 jh x 2 b; 256 threads each.
    int idx = blockIdx.x - 1600;                      // 0..95
    int kc = idx % 24;
    int rest = idx / 24;                              // 0..3
    int jh = rest & 1;
    int b  = rest >> 1;
    int j = jh * 256 + threadIdx.x;
    const float* xb = x + b * 3072 + kc * 128;        // uniform -> s_load
    const float* W  = We1 + (kc * 128) * 512 + j;
    float acc = 0.f;
#pragma unroll 8
    for (int k = 0; k < 128; ++k) acc += xb[k] * W[k * 512];
    h1part[kc * 1024 + b * 512 + j] = acc;            // non-atomic partial
  }
}

// ---------------- KB: encoder tail (h1->h2->z->zw), k-split latency killer --------
// 2 blocks (one per batch) x 512 threads. Every phase splits K across q
// sub-chunks so all global loads issue concurrently; LDS partial-reduce.
// Also zeroes out[0].
__global__ __launch_bounds__(512) void kB_enc(
    const float* __restrict__ h1part, const float* __restrict__ be1,
    const float* __restrict__ We2, const float* __restrict__ be2,
    const float* __restrict__ We3, const float* __restrict__ be3,
    const float* __restrict__ Wd1, const float* __restrict__ bd1,
    float* __restrict__ zw, float* __restrict__ out) {
  __shared__ float h1l[512];
  __shared__ float h2p[512];
  __shared__ float h2l[128];
  __shared__ float zp[512];
  __shared__ float zl[64];
  __shared__ float wp[512];
  int b = blockIdx.x;
  int t = threadIdx.x;
  if (b == 0 && t == 0) out[0] = 0.f;
  // h1[k] = relu(be1[k] + sum_kc h1part[kc][b][k]); one k per thread.
  {
    float a = be1[t];
#pragma unroll
    for (int kc = 0; kc < 24; ++kc) a += h1part[kc * 1024 + b * 512 + t];
    h1l[t] = fmaxf(a, 0.f);
  }
  __syncthreads();
  // h2 partials: thread (q<4, j<128) does K-slice [128q,128q+128).
  {
    int q = t >> 7, j = t & 127;
    const float* W = We2 + (q * 128) * 128 + j;
    const float* h = h1l + q * 128;
    float a = 0.f;
#pragma unroll 16
    for (int k = 0; k < 128; ++k) a += h[k] * W[k * 128];
    h2p[t] = a;
  }
  __syncthreads();
  if (t < 128)
    h2l[t] = fmaxf(h2p[t] + h2p[128 + t] + h2p[256 + t] + h2p[384 + t]
                   + be2[t], 0.f);
  __syncthreads();
  // z partials: thread (q<8, j<64) does K-slice of 16.
  {
    int q = t >> 6, j = t & 63;
    float a = 0.f;
#pragma unroll
    for (int kk = 0; kk < 16; ++kk) {
      int k = q * 16 + kk;
      a += h2l[k] * We3[k * 64 + j];
    }
    zp[t] = a;
  }
  __syncthreads();
  if (t < 64) {
    float a = be3[t];
#pragma unroll
    for (int q = 0; q < 8; ++q) a += zp[q * 64 + t];
    zl[t] = fmaxf(a, 0.f);
  }
  __syncthreads();
  // zw partials: thread (q<4, j<128) does K-slice of 16 over Wd1 rows 0..63.
  {
    int q = t >> 7, j = t & 127;
    float a = 0.f;
#pragma unroll
    for (int kk = 0; kk < 16; ++kk) {
      int k = q * 16 + kk;
      a += zl[k] * Wd1[k * 128 + j];
    }
    wp[t] = a;
  }
  __syncthreads();
  if (t < 128)
    zw[b * 128 + t] = wp[t] + wp[128 + t] + wp[256 + t] + wp[384 + t]
                      + bd1[t];
}

// ---------------- KC: dec2 + dec3 + tanh + (-2y,|y|^2) pack ----------------
// 256 blocks = rt(16) x pg(16); 512 threads = 8 waves.
// Phase A: d1 = relu(zw+gw) for this block's 8 rows (elementwise).
// Phase B: dec2 inline -> a_lds (thread = column j, 8 rows reuse each Wd2 word).
// Phase C: dec3 k-split: wave w owns k4 range [16w,16w+16) for ALL 8 rows ->
// each Wt4 word loaded exactly once per block; LDS partial-combine.
__global__ __launch_bounds__(512) void kC_dec23_y4(
    const float* __restrict__ zw, const float* __restrict__ gw,
    const float* __restrict__ Wd2, const float* __restrict__ bd2,
    const float4* __restrict__ Wt4, const float* __restrict__ bd3,
    float4* __restrict__ Y4) {
  __shared__ float4 a_lds[8 * 128];        // 8 rows x 512 k = 16 KB
  __shared__ float part[8 * 3 * 8 * 64];   // [r][c][w][lane] = 48 KB
  __shared__ float d1l[8 * 128];           // 4 KB
  int rt = blockIdx.x >> 4;
  int pg = blockIdx.x & 15;
  int t = threadIdx.x;
  // Phase A: d1 for rows rt*8..rt*8+7
#pragma unroll
  for (int i = 0; i < 2; ++i) {
    int idx = i * 512 + t;
    int r = idx >> 7, kk = idx & 127;
    int row = rt * 8 + r, b = row >> 6, g = row & 63;
    d1l[idx] = fmaxf(zw[b * 128 + kk] + gw[g * 128 + kk], 0.f);
  }
  __syncthreads();
  // Phase B: dec2 -> a_lds rows (thread = output column j)
  {
    float* a_f = (float*)a_lds;
    int j = t;
    float bj = bd2[j];
    float acc[8];
#pragma unroll
    for (int r = 0; r < 8; ++r) acc[r] = bj;
#pragma unroll 8
    for (int k = 0; k < 128; ++k) {
      float wv = Wd2[k * 512 + j];
#pragma unroll
      for (int r = 0; r < 8; ++r) acc[r] += d1l[r * 128 + k] * wv;
    }
#pragma unroll
    for (int r = 0; r < 8; ++r) a_f[r * 512 + j] = fmaxf(acc[r], 0.f);
  }
  __syncthreads();
  // Phase C: dec3
  int lane = t & 63, w = t >> 6;           // w = 0..7
  int p = pg * 64 + lane;
  const float4* wp0 = Wt4 + p;             // c=0
  const float4* wp1 = Wt4 + 131072 + p;    // c=1
  const float4* wp2 = Wt4 + 262144 + p;    // c=2
  float acc[8][3];
#pragma unroll
  for (int r = 0; r < 8; ++r)
#pragma unroll
    for (int c = 0; c < 3; ++c) acc[r][c] = 0.f;
  int kbase = w * 16;
#pragma unroll 4
  for (int i = 0; i < 16; ++i) {
    int k4 = kbase + i;
    float4 w0 = wp0[k4 * 1024];
    float4 w1 = wp1[k4 * 1024];
    float4 w2 = wp2[k4 * 1024];
#pragma unroll
    for (int r = 0; r < 8; ++r) {
      float4 A = a_lds[r * 128 + k4];      // wave-uniform broadcast
      acc[r][0] += A.x * w0.x + A.y * w0.y + A.z * w0.z + A.w * w0.w;
      acc[r][1] += A.x * w1.x + A.y * w1.y + A.z * w1.z + A.w * w1.w;
      acc[r][2] += A.x * w2.x + A.y * w2.y + A.z * w2.z + A.w * w2.w;
    }
  }
#pragma unroll
  for (int r = 0; r < 8; ++r)
#pragma unroll
    for (int c = 0; c < 3; ++c)
      part[((r * 3 + c) * 8 + w) * 64 + lane] = acc[r][c];
  __syncthreads();
  // combine: thread (w,lane) -> output row w, col p
  {
    int r = w;
    float s0 = 0.f, s1 = 0.f, s2 = 0.f;
#pragma unroll
    for (int ww = 0; ww < 8; ++ww) {
      s0 += part[((r * 3 + 0) * 8 + ww) * 64 + lane];
      s1 += part[((r * 3 + 1) * 8 + ww) * 64 + lane];
      s2 += part[((r * 3 + 2) * 8 + ww) * 64 + lane];
    }
    float b0 = bd3[p * 3], b1 = bd3[p * 3 + 1], b2 = bd3[p * 3 + 2];
    float y0 = tanhf(s0 + b0), y1 = tanhf(s1 + b1), y2 = tanhf(s2 + b2);
    int row = rt * 8 + r;
    Y4[row * 1024 + p] = make_float4(-2.f * y0, -2.f * y1, -2.f * y2,
                                     y0 * y0 + y1 * y1 + y2 * y2);
  }
}

// ---------------- KD: merged chamfer, 4 insts/pair (unchanged hot loop) ----------------
// blocks 0..255: dir1 (sum_n min_m), blocks 256..511: dir2 partial mins.
// Exactly 2048 waves = 2 waves/SIMD.
__global__ __launch_bounds__(256) void kD_chamfer(
    const float4* __restrict__ Y4, const float4* __restrict__ S4,
    float* __restrict__ mpart, float* __restrict__ out) {
  __shared__ float4 c_lds[1024];           // 16 KB inner cloud
  int t = threadIdx.x;
  if (blockIdx.x < 256) {
    // ---- dir1: resident my = (-2y, |y|^2); LDS = S (plain, |s|^2) ----
    int b = blockIdx.x >> 7, nt = blockIdx.x & 127;
    {
      const float4* src = S4 + b * 1024;
#pragma unroll
      for (int i = 0; i < 4; ++i) c_lds[i * 256 + t] = src[i * 256 + t];
    }
    float4 my0 = Y4[b * 65536 + nt * 512 + t];
    float4 my1 = Y4[b * 65536 + nt * 512 + 256 + t];
    __syncthreads();
    float mn0 = __builtin_inff(), mn1 = mn0;
#pragma unroll 8
    for (int m = 0; m < 1024; ++m) {
      float4 s = c_lds[m];                 // block-uniform broadcast
      float d0 = __builtin_fmaf(s.x, my0.x,
                 __builtin_fmaf(s.y, my0.y,
                 __builtin_fmaf(s.z, my0.z, s.w)));
      float d1 = __builtin_fmaf(s.x, my1.x,
                 __builtin_fmaf(s.y, my1.y,
                 __builtin_fmaf(s.z, my1.z, s.w)));
      mn0 = fminf(mn0, d0);
      mn1 = fminf(mn1, d1);
    }
    float v = (mn0 + my0.w) + (mn1 + my1.w);
#pragma unroll
    for (int off = 32; off > 0; off >>= 1) v += __shfl_down(v, off);
    __shared__ float bsum[4];
    int lane = t & 63, w = t >> 6;
    if (lane == 0) bsum[w] = v;
    __syncthreads();
    if (t == 0) atomicAdd(out, bsum[0] + bsum[1] + bsum[2] + bsum[3]);
  } else {
    // ---- dir2: resident s (plain); LDS = Y' = (-2y, |y|^2) ----
    int blk = blockIdx.x - 256;            // 0..255
    int b   = blk >> 7;
    int mg  = (blk >> 6) & 1;
    int nch = blk & 63;
    {
      const float4* src = Y4 + b * 65536 + nch * 1024;
#pragma unroll
      for (int i = 0; i < 4; ++i) c_lds[i * 256 + t] = src[i * 256 + t];
    }
    float4 s0 = S4[b * 1024 + mg * 512 + t];
    float4 s1 = S4[b * 1024 + mg * 512 + 256 + t];
    __syncthreads();
    float mn0 = __builtin_inff(), mn1 = mn0;
#pragma unroll 8
    for (int n = 0; n < 1024; ++n) {
      float4 y = c_lds[n];
      float d0 = __builtin_fmaf(y.x, s0.x,
                 __builtin_fmaf(y.y, s0.y,
                 __builtin_fmaf(y.z, s0.z, y.w)));
      float d1 = __builtin_fmaf(y.x, s1.x,
                 __builtin_fmaf(y.y, s1.y,
                 __builtin_fmaf(y.z, s1.z, y.w)));
      mn0 = fminf(mn0, d0);
      mn1 = fminf(mn1, d1);
    }
    int base = (nch * 2 + b) * 1024 + mg * 512;
    mpart[base + t]       = mn0 + s0.w;
    mpart[base + 256 + t] = mn1 + s1.w;
  }
}

// ---------------- KE: dir2 final reduce ----------------
// 8 blocks x 256; thread = one (b,m); min over 64 chunks then sum.
__global__ __launch_bounds__(256) void kE_dir2_reduce(
    const float* __restrict__ mpart, float* __restrict__ out) {
  int gid = blockIdx.x * 256 + threadIdx.x;   // 0..2047
  int b = gid >> 10, m = gid & 1023;
  float v = __builtin_inff();
#pragma unroll 8
  for (int ch = 0; ch < 64; ++ch)
    v = fminf(v, mpart[(ch * 2 + b) * 1024 + m]);  // coalesced over m
#pragma unroll
  for (int off = 32; off > 0; off >>= 1) v += __shfl_down(v, off);
  __shared__ float bsum[4];
  int lane = threadIdx.x & 63, w = threadIdx.x >> 6;
  if (lane == 0) bsum[w] = v;
  __syncthreads();
  if (threadIdx.x == 0) atomicAdd(out, bsum[0] + bsum[1] + bsum[2] + bsum[3]);
}

extern "C" void kernel_launch(void* const* d_in, const int* in_sizes, int n_in,
                              void* d_out, int out_size, void* d_ws, size_t ws_size,
                              hipStream_t stream) {
  const float* x   = (const float*)d_in[0];
  const float* grd = (const float*)d_in[1];
  const float* We1 = (const float*)d_in[2];
  const float* be1 = (const float*)d_in[3];
  const float* We2 = (const float*)d_in[4];
  const float* be2 = (const float*)d_in[5];
  const float* We3 = (const float*)d_in[6];
  const float* be3 = (const float*)d_in[7];
  const float* Wd1 = (const float*)d_in[8];
  const float* bd1 = (const float*)d_in[9];
  const float* Wd2 = (const float*)d_in[10];
  const float* bd2 = (const float*)d_in[11];
  const float* Wd3 = (const float*)d_in[12];
  const float* bd3 = (const float*)d_in[13];
  float* ws = (float*)d_ws;
  float* out = (float*)d_out;

  float* gw     = ws + OFF_GW;
  float* h1part = ws + OFF_H1P;
  float* zw     = ws + OFF_ZW;
  float* S4     = ws + OFF_S4;
  float* Y4     = ws + OFF_Y4;
  float4* Wt4   = (float4*)(ws + OFF_WT4);
  float* mpart  = ws + OFF_MPART;

  hipLaunchKernelGGL(kA_init, dim3(1696), dim3(256), 0, stream,
                     x, grd, Wd1, Wd3, We1, gw, S4, Wt4, h1part);
  hipLaunchKernelGGL(kB_enc, dim3(2), dim3(512), 0, stream,
                     h1part, be1, We2, be2, We3, be3, Wd1, bd1, zw, out);
  hipLaunchKernelGGL(kC_dec23_y4, dim3(256), dim3(512), 0, stream,
                     zw, gw, Wd2, bd2, Wt4, bd3, (float4*)Y4);
  hipLaunchKernelGGL(kD_chamfer, dim3(512), dim3(256), 0, stream,
                     (const float4*)Y4, (const float4*)S4, mpart, out);
  hipLaunchKernelGGL(kE_dir2_reduce, dim3(8), dim3(256), 0, stream,
                     mpart, out);
}